// Round 1
// baseline (227.870 us; speedup 1.0000x reference)
//
#include <hip/hip_runtime.h>
#include <math.h>

#define VOCAB 32000
#define D 768
#define S 512
#define W 300
#define B 64
#define LMAX 4

// ---------------------------------------------------------------------------
// Kernel 1: per-batch "first break" scan.
// brk[w] = (en < S) && (span <= 0); first[b] = min w with brk, else W.
// fill_id[b] = wid[b, clip(first, 0, W-1)].
// 64 blocks (one per batch) x 64 lanes.
// ---------------------------------------------------------------------------
__global__ __launch_bounds__(64) void find_first_kernel(
    const int* __restrict__ word_index,  // (B, W, 3)
    int* __restrict__ first_out,         // (B)
    int* __restrict__ fill_id_out)       // (B)
{
    const int b = blockIdx.x;
    const int lane = threadIdx.x;  // 0..63
    int my_first = W;
    for (int w = lane; w < W; w += 64) {
        const int base = (b * W + w) * 3;
        const int st = word_index[base + 1];
        const int en = word_index[base + 2];
        const int span = en - st;
        if (en < S && span <= 0) my_first = min(my_first, w);
    }
    // wave=64 reduction (min)
    #pragma unroll
    for (int off = 32; off > 0; off >>= 1)
        my_first = min(my_first, __shfl_xor(my_first, off));
    if (lane == 0) {
        first_out[b] = my_first;
        const int fw = min(my_first, W - 1);
        fill_id_out[b] = word_index[(b * W + fw) * 3 + 0];
    }
}

// ---------------------------------------------------------------------------
// Kernel 2: one wave per (b, w).
// Each lane holds 3 float4 (12 floats) of every 768-float row:
// element index = lane*4 + k*256 (k=0..2) -> fully coalesced 16B/lane loads.
// All branches are wave-uniform (one word per wave).
// ---------------------------------------------------------------------------
__global__ __launch_bounds__(256) void pool_kernel(
    const float* __restrict__ ernie,      // (B, S, D)
    const float* __restrict__ emb,        // (VOCAB, D)
    const int*   __restrict__ word_index, // (B, W, 3)
    const int*   __restrict__ first_arr,  // (B)
    const int*   __restrict__ fill_arr,   // (B)
    float* __restrict__ out)              // (B, W, D)
{
    const int gwave = (int)((blockIdx.x * blockDim.x + threadIdx.x) >> 6);
    const int lane = threadIdx.x & 63;
    if (gwave >= B * W) return;
    const int b = gwave / W;
    const int w = gwave - b * W;

    const int base = (b * W + w) * 3;
    const int wid = word_index[base + 0];
    const int st  = word_index[base + 1];
    const int en  = word_index[base + 2];
    const int span = en - st;

    float4* __restrict__ outp = (float4*)(out + ((size_t)(b * W + w)) * D);

    // ---- fill path: w >= first[b] -> out = emb[fill_id] ----
    if (w >= first_arr[b]) {
        const float4* src = (const float4*)(emb + (size_t)fill_arr[b] * D);
        #pragma unroll
        for (int k = 0; k < 3; k++) outp[lane + 64 * k] = src[lane + 64 * k];
        return;
    }

    // ---- load word embedding row (needed by both remaining paths) ----
    const float4* wep = (const float4*)(emb + (size_t)wid * D);
    float4 we[3];
    #pragma unroll
    for (int k = 0; k < 3; k++) we[k] = wep[lane + 64 * k];

    // ---- out-of-range path: en >= S -> out = we ----
    if (en >= S) {
        #pragma unroll
        for (int k = 0; k < 3; k++) outp[lane + 64 * k] = we[k];
        return;
    }

    // ---- pooling path ----
    // reference: mask = l < max(span, 1); span in-range here is >= 1
    // (span<=0 && en<S would have triggered the fill path via first[b]).
    const int span_eff = min(max(span, 1), LMAX);

    float4 ch[LMAX][3];
    float dot[LMAX];
    #pragma unroll
    for (int l = 0; l < LMAX; l++) {
        dot[l] = -INFINITY;
        if (l < span_eff) {
            int pos = st + l;
            pos = min(max(pos, 0), S - 1);  // pos_c clip (defensive)
            const float4* cp = (const float4*)(ernie + ((size_t)b * S + pos) * D);
            float p = 0.f;
            #pragma unroll
            for (int k = 0; k < 3; k++) {
                ch[l][k] = cp[lane + 64 * k];
                p += ch[l][k].x * we[k].x + ch[l][k].y * we[k].y +
                     ch[l][k].z * we[k].z + ch[l][k].w * we[k].w;
            }
            // wave=64 sum reduction; afterwards every lane holds the full dot
            #pragma unroll
            for (int off = 32; off > 0; off >>= 1) p += __shfl_xor(p, off);
            dot[l] = p;
        }
    }

    // softmax over the valid l's (scalar, replicated across lanes)
    float m = -INFINITY;
    #pragma unroll
    for (int l = 0; l < LMAX; l++)
        if (l < span_eff) m = fmaxf(m, dot[l]);
    float a[LMAX];
    float denom = 0.f;
    #pragma unroll
    for (int l = 0; l < LMAX; l++) {
        a[l] = (l < span_eff) ? expf(dot[l] - m) : 0.f;
        denom += a[l];
    }
    const float inv = 1.f / denom;

    float4 acc[3];
    #pragma unroll
    for (int k = 0; k < 3; k++) acc[k] = make_float4(0.f, 0.f, 0.f, 0.f);
    #pragma unroll
    for (int l = 0; l < LMAX; l++) {
        if (l < span_eff) {
            const float al = a[l] * inv;
            #pragma unroll
            for (int k = 0; k < 3; k++) {
                acc[k].x += al * ch[l][k].x;
                acc[k].y += al * ch[l][k].y;
                acc[k].z += al * ch[l][k].z;
                acc[k].w += al * ch[l][k].w;
            }
        }
    }
    #pragma unroll
    for (int k = 0; k < 3; k++) outp[lane + 64 * k] = acc[k];
}

extern "C" void kernel_launch(void* const* d_in, const int* in_sizes, int n_in,
                              void* d_out, int out_size, void* d_ws, size_t ws_size,
                              hipStream_t stream) {
    const float* ernie      = (const float*)d_in[0];  // (B, S, D) fp32
    const float* emb        = (const float*)d_in[1];  // (VOCAB, D) fp32
    const int*   word_index = (const int*)d_in[2];    // (B, W, 3) int32
    float* out = (float*)d_out;                       // (B, W, D) fp32

    int* first_arr = (int*)d_ws;        // B ints
    int* fill_arr  = first_arr + B;     // B ints

    find_first_kernel<<<B, 64, 0, stream>>>(word_index, first_arr, fill_arr);

    const int total_waves = B * W;                 // 19200
    const int waves_per_block = 4;                 // 256 threads
    const int grid = (total_waves + waves_per_block - 1) / waves_per_block;
    pool_kernel<<<grid, 256, 0, stream>>>(ernie, emb, word_index,
                                          first_arr, fill_arr, out);
}

// Round 2
// 227.059 us; speedup vs baseline: 1.0036x; 1.0036x over previous
//
#include <hip/hip_runtime.h>
#include <math.h>

#define VOCAB 32000
#define D 768
#define S 512
#define W 300
#define B 64
#define LMAX 4

typedef float f32x4 __attribute__((ext_vector_type(4)));

// ---------------------------------------------------------------------------
// Kernel 1: per-batch "first break" scan.
// brk[w] = (en < S) && (span <= 0); first[b] = min w with brk, else W.
// fill_id[b] = wid[b, clip(first, 0, W-1)].
// ---------------------------------------------------------------------------
__global__ __launch_bounds__(64) void find_first_kernel(
    const int* __restrict__ word_index,  // (B, W, 3)
    int* __restrict__ first_out,         // (B)
    int* __restrict__ fill_id_out)       // (B)
{
    const int b = blockIdx.x;
    const int lane = threadIdx.x;  // 0..63
    int my_first = W;
    for (int w = lane; w < W; w += 64) {
        const int base = (b * W + w) * 3;
        const int st = word_index[base + 1];
        const int en = word_index[base + 2];
        if (en < S && (en - st) <= 0) my_first = min(my_first, w);
    }
    #pragma unroll
    for (int off = 32; off > 0; off >>= 1)
        my_first = min(my_first, __shfl_xor(my_first, off));
    if (lane == 0) {
        first_out[b] = my_first;
        const int fw = min(my_first, W - 1);
        fill_id_out[b] = word_index[(b * W + fw) * 3 + 0];
    }
}

__device__ __forceinline__ float wave_bcast_sum(float p) {
    #pragma unroll
    for (int off = 32; off > 0; off >>= 1) p += __shfl_xor(p, off);
    return p;
}

// ---------------------------------------------------------------------------
// Kernel 2: one wave per (b, w), online-softmax single pass over char rows.
// Each lane holds 3 f32x4 (12 floats) of every 768-float row:
// element idx = lane*4 + k*256 -> fully coalesced 16B/lane loads.
// gwave forced wave-uniform via readfirstlane -> scalar idx loads + scalar
// branches. Char rows consumed immediately (no regs held across phases),
// peak live set ~55 VGPRs -> no scratch spills.
// ---------------------------------------------------------------------------
__global__ __launch_bounds__(256) void pool_kernel(
    const float* __restrict__ ernie,      // (B, S, D)
    const float* __restrict__ emb,        // (VOCAB, D)
    const int*   __restrict__ word_index, // (B, W, 3)
    const int*   __restrict__ first_arr,  // (B)
    const int*   __restrict__ fill_arr,   // (B)
    float* __restrict__ out)              // (B, W, D)
{
    int gwave = (int)((blockIdx.x * blockDim.x + threadIdx.x) >> 6);
    gwave = __builtin_amdgcn_readfirstlane(gwave);  // force wave-uniform/SGPR
    const int lane = threadIdx.x & 63;

    const int b = gwave / W;
    const int w = gwave - b * W;

    const int base = gwave * 3;
    const int wid = word_index[base + 0];  // scalar loads (uniform address)
    const int st  = word_index[base + 1];
    const int en  = word_index[base + 2];

    f32x4* __restrict__ outp = (f32x4*)(out + (size_t)gwave * D);

    // ---- fill path: w >= first[b] -> out = emb[fill_id] ----
    if (w >= first_arr[b]) {
        const f32x4* src = (const f32x4*)(emb + (size_t)fill_arr[b] * D);
        #pragma unroll
        for (int k = 0; k < 3; k++)
            __builtin_nontemporal_store(src[lane + 64 * k], &outp[lane + 64 * k]);
        return;
    }

    // ---- word embedding row (both remaining paths need it) ----
    const f32x4* wep = (const f32x4*)(emb + (size_t)wid * D);
    f32x4 we0 = wep[lane], we1 = wep[lane + 64], we2 = wep[lane + 128];

    // ---- out-of-range path: en >= S -> out = we ----
    if (en >= S) {
        __builtin_nontemporal_store(we0, &outp[lane]);
        __builtin_nontemporal_store(we1, &outp[lane + 64]);
        __builtin_nontemporal_store(we2, &outp[lane + 128]);
        return;
    }

    // ---- pooling path: online softmax, single pass over char rows ----
    const int span_eff = min(max(en - st, 1), LMAX);
    const f32x4* erow = (const f32x4*)(ernie + (size_t)b * S * D);  // 192 f32x4/row

    float m = -INFINITY, denom = 0.f;
    f32x4 acc0 = 0.f, acc1 = 0.f, acc2 = 0.f;

    int p0 = min(max(st, 0), S - 1);
    f32x4 c0 = erow[p0 * 192 + lane];
    f32x4 c1 = erow[p0 * 192 + lane + 64];
    f32x4 c2 = erow[p0 * 192 + lane + 128];

    #pragma unroll
    for (int l = 0; l < LMAX; ++l) {
        if (l >= span_eff) break;  // scalar branch (span_eff is SGPR)
        f32x4 n0, n1, n2;
        if (l + 1 < span_eff) {    // depth-1 prefetch of next row
            int pn = min(max(st + l + 1, 0), S - 1);
            n0 = erow[pn * 192 + lane];
            n1 = erow[pn * 192 + lane + 64];
            n2 = erow[pn * 192 + lane + 128];
        } else {
            n0 = c0; n1 = c1; n2 = c2;
        }
        f32x4 pv = c0 * we0 + c1 * we1 + c2 * we2;
        float p = pv.x + pv.y + pv.z + pv.w;
        p = wave_bcast_sum(p);          // all lanes hold full dot
        float mn = fmaxf(m, p);
        float scale = expf(m - mn);     // 1st iter: expf(-inf)=0
        float e = expf(p - mn);
        denom = denom * scale + e;
        acc0 = acc0 * scale + e * c0;
        acc1 = acc1 * scale + e * c1;
        acc2 = acc2 * scale + e * c2;
        m = mn;
        c0 = n0; c1 = n1; c2 = n2;
    }

    const float inv = 1.f / denom;
    __builtin_nontemporal_store(acc0 * inv, &outp[lane]);
    __builtin_nontemporal_store(acc1 * inv, &outp[lane + 64]);
    __builtin_nontemporal_store(acc2 * inv, &outp[lane + 128]);
}

extern "C" void kernel_launch(void* const* d_in, const int* in_sizes, int n_in,
                              void* d_out, int out_size, void* d_ws, size_t ws_size,
                              hipStream_t stream) {
    const float* ernie      = (const float*)d_in[0];  // (B, S, D) fp32
    const float* emb        = (const float*)d_in[1];  // (VOCAB, D) fp32
    const int*   word_index = (const int*)d_in[2];    // (B, W, 3) int32
    float* out = (float*)d_out;                       // (B, W, D) fp32

    int* first_arr = (int*)d_ws;        // B ints
    int* fill_arr  = first_arr + B;     // B ints

    find_first_kernel<<<B, 64, 0, stream>>>(word_index, first_arr, fill_arr);

    const int total_waves = B * W;                 // 19200, exact multiple of 4
    const int grid = total_waves / 4;              // 256-thread blocks
    pool_kernel<<<grid, 256, 0, stream>>>(ernie, emb, word_index,
                                          first_arr, fill_arr, out);
}